// Round 12
// baseline (264.152 us; speedup 1.0000x reference)
//
#include <hip/hip_runtime.h>
#include <hip/hip_bf16.h>
#include <stdint.h>

// AttentiveFP readout: B=2048 graphs x (48 real + 1 virtual) nodes, D=256, H=8, DH=32, 4 steps.
// Round-12: BARRIER-FREE fused_step. Each wave owns one graph AND its own private LDS
// double buffer: it stages 8KB strips (16 cols, even/odd paired) via global_load_lds and
// runs a per-wave counted-vmcnt pipeline -- zero s_barrier in the kernel, so the 2 waves
// per block (and 8 waves/CU) interleave as fully independent DMA+compute streams.
// Strip pairs (even/odd cols of a 32-col window) preserve u16x2 epilogue stores.
// E-phase folded attention (WGAS), e_dst fold (WGAD in prep/gru), sv via small GEMM,
// merged gates GEMM, projection GEMM -- all as round 11.

#define NEG_SLOPE 0.2f

typedef unsigned short u16;
typedef short s16x8 __attribute__((ext_vector_type(8)));
typedef float f32x4 __attribute__((ext_vector_type(4)));
typedef float f32x2 __attribute__((ext_vector_type(2)));
typedef u16 u16x2 __attribute__((ext_vector_type(2)));
typedef u16 u16x4 __attribute__((ext_vector_type(4)));
typedef u16 u16x8 __attribute__((ext_vector_type(8)));

__device__ __forceinline__ u16 f2bf(float f) {
  union { float f; uint32_t u; } v; v.f = f;
  uint32_t r = (v.u + 0x7FFFu + ((v.u >> 16) & 1u)) >> 16;  // RNE
  return (u16)r;
}
__device__ __forceinline__ float bf2f(u16 h) {
  union { uint32_t u; float f; } v; v.u = ((uint32_t)h) << 16;
  return v.f;
}

__device__ __forceinline__ void gload_lds16(const void* g, void* l) {
  __builtin_amdgcn_global_load_lds(
      (const __attribute__((address_space(1))) void*)g,
      (__attribute__((address_space(3))) void*)l, 16, 0, 0);
}

__device__ __forceinline__ float redsum_lk(float v) {
  v += __shfl_xor(v, 16); v += __shfl_xor(v, 32);
  return v;
}
__device__ __forceinline__ float redmax_lk(float v) {
  v = fmaxf(v, __shfl_xor(v, 16)); v = fmaxf(v, __shfl_xor(v, 32));
  return v;
}
__device__ __forceinline__ float redsum_wave(float v) {
  v += __shfl_xor(v, 1); v += __shfl_xor(v, 2); v += __shfl_xor(v, 4);
  v += __shfl_xor(v, 8); v += __shfl_xor(v, 16); v += __shfl_xor(v, 32);
  return v;
}

// ---------------------------------------------------------------------------
// FUSED step: 1024 blocks x 128 threads (2 waves); wave w owns graph blockIdx*2+w.
// NS strips of 16 cols (8KB each). Strips 0..15 = Wg (head h = pair 2h,2h+1),
// strips 16..31 = Ws (x' window u = pair 16+2u,17+2u). Even strip = even cols
// (n = win*32 + 2*lr), odd strip = odd cols (+1). Wave-private dbuf, NO barriers.
// ---------------------------------------------------------------------------
template<int NS>
__global__ __launch_bounds__(128, 2)
void fused_step(const u16* __restrict__ X, const u16* __restrict__ BP,
                const u16* __restrict__ EP, const float* __restrict__ SV,
                const float* __restrict__ ED, u16* __restrict__ GS,
                u16* __restrict__ Xn) {
  __shared__ u16 ldsB[2][2][4096];     // [wave][buf] 8KB strips, wave-private
  __shared__ float alphaL[2][8][48];   // per-wave normalized attention weights
  const int tid = threadIdx.x;
  const int w = tid >> 6, l = tid & 63, lr = l & 15, lk = l >> 4;
  const int b = blockIdx.x * 2 + w;
  const u16* Xg = X + (size_t)b * 48 * 256;

  // Per-wave stage of one 8KB strip (8 x 1KB gload_lds, linear).
#define STAGE(S, BUF)                                                          \
  {                                                                            \
    _Pragma("unroll") for (int i_ = 0; i_ < 8; ++i_)                           \
        gload_lds16(BP + ((size_t)(S)*512 + i_ * 64 + l) * 8,                  \
                    &ldsB[w][BUF][i_ * 512]);                                  \
  }

  // ---- prologue: all global->reg loads, one drain ----
  s16x8 af[8][3];
#pragma unroll
  for (int kc = 0; kc < 8; ++kc)
#pragma unroll
    for (int mi = 0; mi < 3; ++mi)
      af[kc][mi] = *(const s16x8*)(Xg + (size_t)(mi * 16 + lr) * 256 + kc * 32 + lk * 8);

  s16x8 be[8];
#pragma unroll
  for (int kc = 0; kc < 8; ++kc)
    be[kc] = *(const s16x8*)(EP + ((size_t)kc * 64 + l) * 8);

  const float edv = ED[(size_t)b * 8 + (l & 7)];
  f32x2 svA[8];
#pragma unroll
  for (int h = 0; h < 8; ++h)
    svA[h] = *(const f32x2*)(SV + (size_t)b * 256 + h * 32 + 2 * lr);

  asm volatile("s_waitcnt vmcnt(0)" ::: "memory");  // vmcnt domain now stage/store-only
  STAGE(0, 0)

  // ---- E-phase: e_src for all 48 nodes x 8 heads via 24 MFMA (hides stage-0) ----
  {
    f32x4 ae[3];
#pragma unroll
    for (int mi = 0; mi < 3; ++mi) ae[mi] = (f32x4){0.f, 0.f, 0.f, 0.f};
#pragma unroll
    for (int kc = 0; kc < 8; ++kc)
#pragma unroll
      for (int mi = 0; mi < 3; ++mi)
        ae[mi] = __builtin_amdgcn_mfma_f32_16x16x32_bf16(af[kc][mi], be[kc], ae[mi], 0, 0, 0);

    if (lr < 8) {  // lane lr owns head lr for its lk-row-group
      float ev[3][4];
      float m = -1e30f;
#pragma unroll
      for (int mi = 0; mi < 3; ++mi)
#pragma unroll
        for (int j = 0; j < 4; ++j) {
          float v = ae[mi][j] + edv;
          v = (v > 0.f) ? v : NEG_SLOPE * v;  // leaky_relu
          ev[mi][j] = v;
          m = fmaxf(m, v);
        }
      m = redmax_lk(m);  // max over all 48 nodes
      float sm = 0.f;
#pragma unroll
      for (int mi = 0; mi < 3; ++mi)
#pragma unroll
        for (int j = 0; j < 4; ++j) {
          float ex = expf(ev[mi][j] - m);
          ev[mi][j] = ex; sm += ex;
        }
      sm = redsum_lk(sm);
      const float inv = 1.f / sm;
#pragma unroll
      for (int mi = 0; mi < 3; ++mi)
#pragma unroll
        for (int j = 0; j < 4; ++j)
          alphaL[w][lr][mi * 16 + lk * 4 + j] = ev[mi][j] * inv;
    }
  }

  // ---- wave-private strip pipeline: counted vmcnt, zero barriers ----
  f32x4 accE[3], accO[3];

#define CONSUME(ACC, BUF)                                                      \
  {                                                                            \
    _Pragma("unroll") for (int mi = 0; mi < 3; ++mi)                           \
        ACC[mi] = (f32x4){0.f, 0.f, 0.f, 0.f};                                 \
    const u16* bufB = &ldsB[w][BUF][0];                                        \
    _Pragma("unroll") for (int kc = 0; kc < 8; ++kc) {                         \
      s16x8 bfr = *(const s16x8*)&bufB[kc * 512 + l * 8];                      \
      _Pragma("unroll") for (int mi = 0; mi < 3; ++mi)                         \
        ACC[mi] = __builtin_amdgcn_mfma_f32_16x16x32_bf16(af[kc][mi], bfr,     \
                                                          ACC[mi], 0, 0, 0);   \
    }                                                                          \
  }

#pragma unroll
  for (int f = 0; f < NS; ++f) {
    // Need STAGE(f) resident. Younger-than-STAGE(f) VMEM (per wave, in order):
    //   f==0 / f odd: nothing (epilogues happen only at odd iters, after STAGE(f+1));
    //   f even>0: stores of pair (f-2,f-1): 1 u16x2 (attn) or 12 u16x2 (Xn).
    if (f == 0 || (f & 1)) { asm volatile("s_waitcnt vmcnt(0)" ::: "memory"); }
    else if (f <= 16)      { asm volatile("s_waitcnt vmcnt(1)" ::: "memory"); }
    else                   { asm volatile("s_waitcnt vmcnt(12)" ::: "memory"); }
    if (f + 1 < NS) STAGE(f + 1, (f + 1) & 1)

    if ((f & 1) == 0) {
      CONSUME(accE, f & 1)
    } else {
      CONSUME(accO, f & 1)
      // ---- pair epilogue ----
      if (f < 16) {
        // attention head h = f>>1: alpha broadcast reads, 1 u16x2 GS store
        const int h = f >> 1;
        float mmE = 0.f, mmO = 0.f;
#pragma unroll
        for (int mi = 0; mi < 3; ++mi)
#pragma unroll
          for (int j = 0; j < 4; ++j) {
            const float a = alphaL[w][h][mi * 16 + lk * 4 + j];
            mmE += a * accE[mi][j];
            mmO += a * accO[mi][j];
          }
        mmE = redsum_lk(mmE);
        mmO = redsum_lk(mmO);
        if (lk == 0) {
          u16x2 o = {f2bf(fmaxf(mmE + svA[h][0], 0.f)),
                     f2bf(fmaxf(mmO + svA[h][1], 0.f))};
          *(u16x2*)(GS + (size_t)b * 512 + h * 32 + 2 * lr) = o;
        }
      } else {
        // Ws window u = (f>>1)-8: relu -> Xn (12 u16x2 stores)
        const int u = (f >> 1) - 8;
#pragma unroll
        for (int mi = 0; mi < 3; ++mi)
#pragma unroll
          for (int j = 0; j < 4; ++j) {
            u16x2 o = {f2bf(fmaxf(accE[mi][j], 0.f)),
                       f2bf(fmaxf(accO[mi][j], 0.f))};
            *(u16x2*)(Xn + (size_t)(b * 48 + mi * 16 + lk * 4 + j) * 256 +
                      u * 32 + 2 * lr) = o;
          }
      }
    }
  }
#undef CONSUME
#undef STAGE
}

// ---------------------------------------------------------------------------
// Generic bf16 GEMM: C[M,N] = A[M,K=256] * Bt[N,K=256]^T, 128x128, pipelined.
// EPI: 0 = f32 store; 2 = f32 + bias (projection).
// ---------------------------------------------------------------------------
template<int EPI>
__global__ __launch_bounds__(256)
void gemm_bt(const u16* __restrict__ A, int lda,
             const u16* __restrict__ Bt,
             float* __restrict__ Cf, int ldc, const float* __restrict__ bias) {
  __shared__ u16 ldsA[2][2 * 128 * 32];
  __shared__ u16 ldsB[2][2 * 128 * 32];
  const int tid = threadIdx.x;
  const int w = tid >> 6, l = tid & 63;
  const int wr = w >> 1, wc = w & 1;
  const int lr = l & 15, lk = l >> 4;
  const int sxor = (lr >> 1) & 3;
  const int m0 = blockIdx.x * 128, n0 = blockIdx.y * 128;

#define STAGE_AB(KT, BUF)                                                      \
  {                                                                            \
    const u16* Ag = A + (size_t)m0 * lda + (KT)*64;                            \
    const u16* Bg = Bt + (size_t)n0 * 256 + (KT)*64;                           \
    _Pragma("unroll") for (int i = 0; i < 4; ++i) {                            \
      int q = i * 256 + tid;                                                   \
      int h2 = q >> 9, r = (q >> 2) & 127, c4 = q & 3;                         \
      int c4s = c4 ^ ((r >> 1) & 3);                                           \
      gload_lds16(Ag + (size_t)r * lda + h2 * 32 + c4s * 8,                    \
                  &ldsA[BUF][(i * 256 + w * 64) * 8]);                         \
      gload_lds16(Bg + (size_t)r * 256 + h2 * 32 + c4s * 8,                    \
                  &ldsB[BUF][(i * 256 + w * 64) * 8]);                         \
    }                                                                          \
  }

  f32x4 acc[4][4];
#pragma unroll
  for (int i = 0; i < 4; ++i)
#pragma unroll
    for (int j = 0; j < 4; ++j) acc[i][j] = (f32x4){0.f, 0.f, 0.f, 0.f};

  STAGE_AB(0, 0)
#pragma unroll
  for (int kt = 0; kt < 4; ++kt) {
    __syncthreads();
    if (kt < 3) STAGE_AB(kt + 1, (kt + 1) & 1)
    const u16* bA = ldsA[kt & 1];
    const u16* bB = ldsB[kt & 1];
#pragma unroll
    for (int hh = 0; hh < 2; ++hh) {
      s16x8 af[4], bfr[4];
#pragma unroll
      for (int mi = 0; mi < 4; ++mi)
        af[mi] = *(const s16x8*)&bA[(hh * 128 + wr * 64 + mi * 16 + lr) * 32 +
                                    (lk ^ sxor) * 8];
#pragma unroll
      for (int ni = 0; ni < 4; ++ni)
        bfr[ni] = *(const s16x8*)&bB[(hh * 128 + wc * 64 + ni * 16 + lr) * 32 +
                                     (lk ^ sxor) * 8];
#pragma unroll
      for (int mi = 0; mi < 4; ++mi)
#pragma unroll
        for (int ni = 0; ni < 4; ++ni)
          acc[mi][ni] = __builtin_amdgcn_mfma_f32_16x16x32_bf16(af[mi], bfr[ni],
                                                                acc[mi][ni], 0, 0, 0);
    }
  }
#undef STAGE_AB

#pragma unroll
  for (int mi = 0; mi < 4; ++mi) {
#pragma unroll
    for (int ni = 0; ni < 4; ++ni) {
      f32x4 v = acc[mi][ni];
      int r = m0 + wr * 64 + mi * 16 + lk * 4;
      int c = n0 + wc * 64 + ni * 16 + lr;
#pragma unroll
      for (int j = 0; j < 4; ++j) {
        float fv = v[j];
        if (EPI == 0) Cf[(size_t)(r + j) * ldc + c] = fv;
        else          Cf[(size_t)(r + j) * ldc + c] = fv + bias[c];
      }
    }
  }
}

// Merged GRU-gate GEMM: blockIdx.y<6 -> G1 = g0@wx ; else G2 = state@wh. Pipelined.
__global__ __launch_bounds__(256)
void gemm_gates(const u16* __restrict__ GS, const u16* __restrict__ WXT,
                const u16* __restrict__ WHT, float* __restrict__ G1,
                float* __restrict__ G2) {
  __shared__ u16 ldsA[2][2 * 128 * 32];
  __shared__ u16 ldsB[2][2 * 128 * 32];
  const bool second = blockIdx.y >= 6;
  const u16* A = GS + (second ? 256 : 0);
  const u16* Bt = second ? WHT : WXT;
  float* Cf = second ? G2 : G1;
  const int n0 = (second ? blockIdx.y - 6 : blockIdx.y) * 128;
  const int m0 = blockIdx.x * 128;
  const int tid = threadIdx.x;
  const int w = tid >> 6, l = tid & 63;
  const int wr = w >> 1, wc = w & 1;
  const int lr = l & 15, lk = l >> 4;
  const int sxor = (lr >> 1) & 3;

#define STAGE_AB(KT, BUF)                                                      \
  {                                                                            \
    const u16* Ag = A + (size_t)m0 * 512 + (KT)*64;                            \
    const u16* Bg = Bt + (size_t)n0 * 256 + (KT)*64;                           \
    _Pragma("unroll") for (int i = 0; i < 4; ++i) {                            \
      int q = i * 256 + tid;                                                   \
      int h2 = q >> 9, r = (q >> 2) & 127, c4 = q & 3;                         \
      int c4s = c4 ^ ((r >> 1) & 3);                                           \
      gload_lds16(Ag + (size_t)r * 512 + h2 * 32 + c4s * 8,                    \
                  &ldsA[BUF][(i * 256 + w * 64) * 8]);                         \
      gload_lds16(Bg + (size_t)r * 256 + h2 * 32 + c4s * 8,                    \
                  &ldsB[BUF][(i * 256 + w * 64) * 8]);                         \
    }                                                                          \
  }

  f32x4 acc[4][4];
#pragma unroll
  for (int i = 0; i < 4; ++i)
#pragma unroll
    for (int j = 0; j < 4; ++j) acc[i][j] = (f32x4){0.f, 0.f, 0.f, 0.f};

  STAGE_AB(0, 0)
#pragma unroll
  for (int kt = 0; kt < 4; ++kt) {
    __syncthreads();
    if (kt < 3) STAGE_AB(kt + 1, (kt + 1) & 1)
    const u16* bA = ldsA[kt & 1];
    const u16* bB = ldsB[kt & 1];
#pragma unroll
    for (int hh = 0; hh < 2; ++hh) {
      s16x8 af[4], bfr[4];
#pragma unroll
      for (int mi = 0; mi < 4; ++mi)
        af[mi] = *(const s16x8*)&bA[(hh * 128 + wr * 64 + mi * 16 + lr) * 32 +
                                    (lk ^ sxor) * 8];
#pragma unroll
      for (int ni = 0; ni < 4; ++ni)
        bfr[ni] = *(const s16x8*)&bB[(hh * 128 + wc * 64 + ni * 16 + lr) * 32 +
                                     (lk ^ sxor) * 8];
#pragma unroll
      for (int mi = 0; mi < 4; ++mi)
#pragma unroll
        for (int ni = 0; ni < 4; ++ni)
          acc[mi][ni] = __builtin_amdgcn_mfma_f32_16x16x32_bf16(af[mi], bfr[ni],
                                                                acc[mi][ni], 0, 0, 0);
    }
  }
#undef STAGE_AB

#pragma unroll
  for (int mi = 0; mi < 4; ++mi) {
#pragma unroll
    for (int ni = 0; ni < 4; ++ni) {
      f32x4 v = acc[mi][ni];
      int r = m0 + wr * 64 + mi * 16 + lk * 4;
      int c = n0 + wc * 64 + ni * 16 + lr;
#pragma unroll
      for (int j = 0; j < 4; ++j)
        Cf[(size_t)(r + j) * 768 + c] = v[j];
    }
  }
}

// One-shot transpose-convert: WST (Ws^T), WXT, WHT, PRJ  (out[N][K] bf16 from in[K][N] f32)
__global__ void pack_all(const float* __restrict__ Ws, const float* __restrict__ wx,
                         const float* __restrict__ wh, const float* __restrict__ pw,
                         u16* __restrict__ WST, u16* __restrict__ WXT,
                         u16* __restrict__ WHT, u16* __restrict__ PRJ) {
  int idx = blockIdx.x * 256 + threadIdx.x;
  const float* src; u16* dst; int N; int li;
  if (idx < 65536)        { src = Ws; dst = WST; N = 256; li = idx; }
  else if (idx < 262144)  { src = wx; dst = WXT; N = 768; li = idx - 65536; }
  else if (idx < 458752)  { src = wh; dst = WHT; N = 768; li = idx - 262144; }
  else                    { src = pw; dst = PRJ; N = 256; li = idx - 458752; }
  int n = li >> 8, k = li & 255;
  dst[li] = f2bf(src[(size_t)k * N + n]);
}

// Fragment-major packing of [Wg | Ws] in 16-col strips, even/odd paired:
// chunk c: l=c&63, kc=(c>>6)&7, s=c>>9 (0..31); window u=s>>1, parity p=s&1;
// col n = u*32 + 2*(l&15) + p  (strips 0-15 -> Wg, 16-31 -> Ws).
__global__ void pack_bp(const float* __restrict__ Wg, const float* __restrict__ Ws,
                        u16* __restrict__ BP) {
  int c = blockIdx.x * 256 + threadIdx.x;  // 16384 chunks
  int l = c & 63, kc = (c >> 6) & 7, s = c >> 9;
  int u = s >> 1, p = s & 1;
  int n = u * 32 + ((l & 15) << 1) + p;
  int k0 = kc * 32 + (l >> 4) * 8;
  const float* W = (n < 256) ? Wg : Ws;
  int nn = n & 255;
  u16x8 o;
#pragma unroll
  for (int e = 0; e < 8; ++e) o[e] = f2bf(W[(size_t)(k0 + e) * 256 + nn]);
  *(u16x8*)(BP + (size_t)c * 8) = o;
}

// WGAD[d][h] = sum_j Wg[d][h*32+j]*adst[h*32+j];  WGAS likewise with asrc.
__global__ void wgad_kernel(const float* __restrict__ Wg, const float* __restrict__ adst,
                            const float* __restrict__ asrc,
                            float* __restrict__ WGAD, float* __restrict__ WGAS) {
  const int h = blockIdx.x, d = threadIdx.x;
  float sd = 0.f, ss = 0.f;
#pragma unroll
  for (int j = 0; j < 32; ++j) {
    float wv = Wg[(size_t)d * 256 + h * 32 + j];
    sd += wv * adst[h * 32 + j];
    ss += wv * asrc[h * 32 + j];
  }
  WGAD[(size_t)d * 8 + h] = sd;
  WGAS[(size_t)d * 8 + h] = ss;
}

// B-fragment pack of WGAS for the E-phase MFMA (heads at cols 0-7; cols 8-15 zero).
__global__ void pack_ep(const float* __restrict__ WGAS, u16* __restrict__ EP) {
  int c = blockIdx.x * 256 + threadIdx.x;  // 512 chunks
  if (c >= 512) return;
  int l = c & 63, kc = c >> 6;
  int hh = l & 15, k0 = kc * 32 + (l >> 4) * 8;
  u16x8 o;
#pragma unroll
  for (int e = 0; e < 8; ++e)
    o[e] = (hh < 8) ? f2bf(WGAS[(size_t)(k0 + e) * 8 + hh]) : (u16)0;
  *(u16x8*)(EP + (size_t)c * 8) = o;
}

// x0 bf16 + virtual sum -> state f32/bf16 + ED (state . WGAD per head)
__global__ __launch_bounds__(256)
void prep_x_kernel(const float* __restrict__ nf, u16* __restrict__ X0,
                   float* __restrict__ state, u16* __restrict__ GS,
                   const float* __restrict__ WGAD, float* __restrict__ ED) {
  __shared__ f32x4 part[4][64];
  __shared__ float stt[256];
  __shared__ float red[4][8];
  const int b = blockIdx.x, t = threadIdx.x;
  const int c4 = t & 63, sg = t >> 6, l = t & 63;
  const f32x4* src = (const f32x4*)(nf + (size_t)b * 48 * 256);
  f32x4 acc = (f32x4){0.f, 0.f, 0.f, 0.f};
  for (int s = sg * 12; s < sg * 12 + 12; ++s) {
    f32x4 v = src[(size_t)s * 64 + c4];
    acc += v;
    u16x4 o = {f2bf(v[0]), f2bf(v[1]), f2bf(v[2]), f2bf(v[3])};
    *(u16x4*)(X0 + ((size_t)b * 48 + s) * 256 + c4 * 4) = o;
  }
  part[sg][c4] = acc;
  __syncthreads();
  if (t < 64) {
    f32x4 r = part[0][t] + part[1][t] + part[2][t] + part[3][t];
#pragma unroll
    for (int j = 0; j < 4; ++j) {
      int d = t * 4 + j;
      stt[d] = r[j];
      state[(size_t)b * 256 + d] = r[j];
      GS[(size_t)b * 512 + 256 + d] = f2bf(r[j]);
    }
  }
  __syncthreads();
  const float st = stt[t];
  float pr[8];
#pragma unroll
  for (int h = 0; h < 8; ++h) pr[h] = redsum_wave(st * WGAD[(size_t)t * 8 + h]);
  if (l == 0) {
#pragma unroll
    for (int h = 0; h < 8; ++h) red[sg][h] = pr[h];
  }
  __syncthreads();
  if (t < 8) ED[(size_t)b * 8 + t] = red[0][t] + red[1][t] + red[2][t] + red[3][t];
}

// GRU elementwise + ED for next step
__global__ void gru_kernel(const float* __restrict__ G1, const float* __restrict__ G2,
                           const float* __restrict__ bx, const float* __restrict__ bh,
                           float* __restrict__ state, u16* __restrict__ GS,
                           const float* __restrict__ WGAD, float* __restrict__ ED) {
  __shared__ float red[4][8];
  const int b = blockIdx.x, d = threadIdx.x;
  const int wv = d >> 6, l = d & 63;
  const float* g1 = G1 + (size_t)b * 768;
  const float* g2 = G2 + (size_t)b * 768;
  float xz = g1[d] + bx[d], xr = g1[256 + d] + bx[256 + d], xh = g1[512 + d] + bx[512 + d];
  float hz = g2[d] + bh[d], hr = g2[256 + d] + bh[256 + d], hh2 = g2[512 + d] + bh[512 + d];
  float z = 1.f / (1.f + expf(-(xz + hz)));
  float r = 1.f / (1.f + expf(-(xr + hr)));
  float n = tanhf(xh + r * hh2);
  float h0 = state[b * 256 + d];
  float sn = z * h0 + (1.f - z) * n;
  state[b * 256 + d] = sn;
  GS[(size_t)b * 512 + 256 + d] = f2bf(sn);
  float pr[8];
#pragma unroll
  for (int h = 0; h < 8; ++h) pr[h] = redsum_wave(sn * WGAD[(size_t)d * 8 + h]);
  if (l == 0) {
#pragma unroll
    for (int h = 0; h < 8; ++h) red[wv][h] = pr[h];
  }
  __syncthreads();
  if (d < 8) ED[(size_t)b * 8 + d] = red[0][d] + red[1][d] + red[2][d] + red[3][d];
}

extern "C" void kernel_launch(void* const* d_in, const int* in_sizes, int n_in,
                              void* d_out, int out_size, void* d_ws, size_t ws_size,
                              hipStream_t stream) {
  const float* nf  = (const float*)d_in[0];
  const float* Wg  = (const float*)d_in[2];
  const float* Ws  = (const float*)d_in[3];
  const float* asr = (const float*)d_in[4];
  const float* ads = (const float*)d_in[5];
  const float* wx  = (const float*)d_in[6];
  const float* wh  = (const float*)d_in[7];
  const float* bx  = (const float*)d_in[8];
  const float* bh  = (const float*)d_in[9];
  const float* pw  = (const float*)d_in[10];
  const float* pb  = (const float*)d_in[11];
  float* out = (float*)d_out;

  char* p = (char*)d_ws;
  size_t off = 0;
  auto alloc = [&](size_t bytes) { char* r = p + off; off += (bytes + 255) & ~255ULL; return r; };
  u16* WST   = (u16*)alloc(256 * 256 * 2);
  u16* WXT   = (u16*)alloc(768 * 256 * 2);
  u16* WHT   = (u16*)alloc(768 * 256 * 2);
  u16* PRJ   = (u16*)alloc(256 * 256 * 2);
  u16* BP    = (u16*)alloc(512 * 256 * 2);            // [Wg|Ws] 16-col strip pack
  u16* EP    = (u16*)alloc(512 * 8 * 2);              // WGAS fragment pack (8KB)
  float* WGAD = (float*)alloc(256 * 8 * 4);
  float* WGAS = (float*)alloc(256 * 8 * 4);
  u16* X0    = (u16*)alloc((size_t)98304 * 256 * 2);
  u16* X1    = (u16*)alloc((size_t)98304 * 256 * 2);
  float* SV   = (float*)alloc((size_t)2048 * 256 * 4);
  float* ED   = (float*)alloc((size_t)2048 * 8 * 4);
  float* G1   = (float*)alloc((size_t)2048 * 768 * 4);
  float* G2   = (float*)alloc((size_t)2048 * 768 * 4);
  u16* GS     = (u16*)alloc((size_t)2048 * 512 * 2);  // [g0 | state] bf16
  float* ST   = (float*)alloc((size_t)2048 * 256 * 4);

  pack_all<<<2048, 256, 0, stream>>>(Ws, wx, wh, pw, WST, WXT, WHT, PRJ);
  pack_bp<<<64, 256, 0, stream>>>(Wg, Ws, BP);
  wgad_kernel<<<8, 256, 0, stream>>>(Wg, ads, asr, WGAD, WGAS);
  pack_ep<<<2, 256, 0, stream>>>(WGAS, EP);
  prep_x_kernel<<<2048, 256, 0, stream>>>(nf, X0, ST, GS, WGAD, ED);

  u16* xc = X0; u16* xn = X1;
  for (int t = 0; t < 4; ++t) {
    // sv = state @ Ws   (M=2048, N=256)
    gemm_bt<0><<<dim3(16, 2), 256, 0, stream>>>(GS + 256, 512, WST, SV, 256, nullptr);
    // fused: h + E-phase attention + g0 (+ xnext for t<3)
    if (t < 3) fused_step<32><<<1024, 128, 0, stream>>>(xc, BP, EP, SV, ED, GS, xn);
    else       fused_step<16><<<1024, 128, 0, stream>>>(xc, BP, EP, SV, ED, GS, nullptr);
    // GRU gates (both in one launch)
    gemm_gates<<<dim3(16, 12), 256, 0, stream>>>(GS, WXT, WHT, G1, G2);
    // GRU elementwise + next-step e_dst
    gru_kernel<<<2048, 256, 0, stream>>>(G1, G2, bx, bh, ST, GS, WGAD, ED);
    u16* tmp = xc; xc = xn; xn = tmp;
  }
  // out = state @ proj_w + proj_b
  gemm_bt<2><<<dim3(16, 2), 256, 0, stream>>>(GS + 256, 512, PRJ, out, 256, pb);
}

// Round 13
// 225.729 us; speedup vs baseline: 1.1702x; 1.1702x over previous
//
#include <hip/hip_runtime.h>
#include <hip/hip_bf16.h>
#include <stdint.h>

// AttentiveFP readout: B=2048 graphs x (48 real + 1 virtual) nodes, D=256, H=8, DH=32, 4 steps.
// Round-13 = round-11 base (best, 254us) + two algebraic folds that delete launches:
//  - sv fold: af gets a 4th row-block = state (dup x16). Ws strips run FIRST; their mi=3
//    row is state@Ws = sv, captured in-register for the later attention strips. The
//    per-step sv GEMM is deleted. t=3 uses LAST variant (Ws strips compute only mi=3).
//  - e_dst fold: EP cols 8-15 = WGAD, so the E-phase (4 mi tiles, 32 MFMA) also yields
//    e_dst[h] = state . WGAD[:,h] at (row48, col 8+h); one __shfl feeds softmax. ED buffer
//    and the ED tails in prep/gru are deleted (gru = pure elementwise).
// fused_step: 1024 blocks x 128 thr (2 waves, wave=graph, shared 16KB strip dbuf with
// barriers + counted vmcnt); E-phase folded attention (WGAS); merged gates GEMM; proj GEMM.

#define NEG_SLOPE 0.2f

typedef unsigned short u16;
typedef short s16x8 __attribute__((ext_vector_type(8)));
typedef float f32x4 __attribute__((ext_vector_type(4)));
typedef float f32x2 __attribute__((ext_vector_type(2)));
typedef u16 u16x2 __attribute__((ext_vector_type(2)));
typedef u16 u16x4 __attribute__((ext_vector_type(4)));
typedef u16 u16x8 __attribute__((ext_vector_type(8)));

__device__ __forceinline__ u16 f2bf(float f) {
  union { float f; uint32_t u; } v; v.f = f;
  uint32_t r = (v.u + 0x7FFFu + ((v.u >> 16) & 1u)) >> 16;  // RNE
  return (u16)r;
}
__device__ __forceinline__ float bf2f(u16 h) {
  union { uint32_t u; float f; } v; v.u = ((uint32_t)h) << 16;
  return v.f;
}

__device__ __forceinline__ void gload_lds16(const void* g, void* l) {
  __builtin_amdgcn_global_load_lds(
      (const __attribute__((address_space(1))) void*)g,
      (__attribute__((address_space(3))) void*)l, 16, 0, 0);
}

__device__ __forceinline__ float redsum_lk(float v) {
  v += __shfl_xor(v, 16); v += __shfl_xor(v, 32);
  return v;
}
__device__ __forceinline__ float redmax_lk(float v) {
  v = fmaxf(v, __shfl_xor(v, 16)); v = fmaxf(v, __shfl_xor(v, 32));
  return v;
}

// ---------------------------------------------------------------------------
// FUSED step: 1024 blocks x 128 threads (2 waves); wave w owns graph blockIdx*2+w.
// 16 strips of 32 cols (16KB, even/odd packed). Processing order: Ws windows
// (BP strips 8..15) FIRST (sv from mi=3), then Wg heads (BP strips 0..7).
// A-frags: mi 0-2 = x rows, mi 3 = state row (dup). E-phase B: WGAS | WGAD.
// ---------------------------------------------------------------------------
template<bool LAST>
__global__ __launch_bounds__(128, 2)
void fused_step(const u16* __restrict__ X, const u16* __restrict__ BP,
                const u16* __restrict__ EP, u16* __restrict__ GS,
                u16* __restrict__ Xn) {
  __shared__ u16 ldsB[2][8192];        // 2 x 16KB strip buffers (fragment-major)
  __shared__ float alphaL[2][8][48];   // per-wave normalized attention weights
  const int tid = threadIdx.x;
  const int w = tid >> 6, l = tid & 63, lr = l & 15, lk = l >> 4;
  const int b = blockIdx.x * 2 + w;
  const u16* Xg = X + (size_t)b * 48 * 256;
  const u16* Sg = GS + (size_t)b * 512 + 256;  // state row (bf16)

#define STAGE(S, BUF)                                                          \
  {                                                                            \
    _Pragma("unroll") for (int i_ = 0; i_ < 8; ++i_)                           \
        gload_lds16(BP + ((size_t)(S)*1024 + i_ * 128 + tid) * 8,              \
                    &ldsB[BUF][(i_ * 128 + w * 64) * 8]);                      \
  }

  // ---- prologue: all global->reg loads, one drain ----
  s16x8 af[8][4];
#pragma unroll
  for (int kc = 0; kc < 8; ++kc) {
#pragma unroll
    for (int mi = 0; mi < 3; ++mi)
      af[kc][mi] = *(const s16x8*)(Xg + (size_t)(mi * 16 + lr) * 256 + kc * 32 + lk * 8);
    af[kc][3] = *(const s16x8*)(Sg + kc * 32 + lk * 8);  // state row (dup over lr)
  }

  s16x8 be[8];
#pragma unroll
  for (int kc = 0; kc < 8; ++kc)
    be[kc] = *(const s16x8*)(EP + ((size_t)kc * 64 + l) * 8);

  asm volatile("s_waitcnt vmcnt(0)" ::: "memory");  // vmcnt domain now stage/store-only
  STAGE(8, 0)  // first processed strip: Ws window 0 (BP strip 8)

  // ---- E-phase: 32 MFMA -> e_src (rows 0-47, cols 0-7) + e_dst (row 48+, cols 8-15) ----
  {
    f32x4 ae[4];
#pragma unroll
    for (int mi = 0; mi < 4; ++mi) ae[mi] = (f32x4){0.f, 0.f, 0.f, 0.f};
#pragma unroll
    for (int kc = 0; kc < 8; ++kc)
#pragma unroll
      for (int mi = 0; mi < 4; ++mi)
        ae[mi] = __builtin_amdgcn_mfma_f32_16x16x32_bf16(af[kc][mi], be[kc], ae[mi], 0, 0, 0);

    // e_dst[h] lives on lane (lr'=8+h, lk=0..3) as ae[3][*] (all rows equal).
    const float edv = __shfl(ae[3][0], 8 + lr);  // valid for lanes lr<8

    if (lr < 8) {  // lane lr owns head lr for its lk-row-group
      float ev[3][4];
      float m = -1e30f;
#pragma unroll
      for (int mi = 0; mi < 3; ++mi)
#pragma unroll
        for (int j = 0; j < 4; ++j) {
          float v = ae[mi][j] + edv;
          v = (v > 0.f) ? v : NEG_SLOPE * v;  // leaky_relu
          ev[mi][j] = v;
          m = fmaxf(m, v);
        }
      m = redmax_lk(m);  // max over all 48 nodes
      float sm = 0.f;
#pragma unroll
      for (int mi = 0; mi < 3; ++mi)
#pragma unroll
        for (int j = 0; j < 4; ++j) {
          float ex = expf(ev[mi][j] - m);
          ev[mi][j] = ex; sm += ex;
        }
      sm = redsum_lk(sm);
      const float inv = 1.f / sm;
#pragma unroll
      for (int mi = 0; mi < 3; ++mi)
#pragma unroll
        for (int j = 0; j < 4; ++j)
          alphaL[w][lr][mi * 16 + lk * 4 + j] = ev[mi][j] * inv;
    }
  }

  f32x2 svA[8];  // sv pairs (cols 2lr, 2lr+1 of each head window), from Ws mi=3

  // ---- strip pipeline: Ws strips (f=0..7, BP 8..15) then Wg strips (f=8..15, BP 0..7) ----
#pragma unroll
  for (int f = 0; f < 16; ++f) {
    // Need STAGE(f) resident. Younger VMEM: stores of strip f-1
    // (Ws: 12 u16x2, or 0 in LAST; Wg: 1 u16x2); f==0: nothing.
    if (f == 0)       { asm volatile("s_waitcnt vmcnt(0)" ::: "memory"); }
    else if (f <= 8)  {
      if (LAST)       { asm volatile("s_waitcnt vmcnt(0)" ::: "memory"); }
      else            { asm volatile("s_waitcnt vmcnt(12)" ::: "memory"); }
    } else            { asm volatile("s_waitcnt vmcnt(1)" ::: "memory"); }
    __builtin_amdgcn_s_barrier();
    if (f + 1 < 16) {
      const int ns = (f + 1 < 8) ? (9 + f) : (f + 1 - 8);
      STAGE(ns, (f + 1) & 1)
    }

    const u16* bufB = ldsB[f & 1];

    if (f < 8) {
      // ---- Ws window u=f: x@Ws (mi 0-2, skipped in LAST) + sv (mi 3) ----
      f32x4 acc[4][2];
#pragma unroll
      for (int mi = 0; mi < 4; ++mi)
#pragma unroll
        for (int ni = 0; ni < 2; ++ni) acc[mi][ni] = (f32x4){0.f, 0.f, 0.f, 0.f};
#pragma unroll
      for (int kc = 0; kc < 8; ++kc) {
        s16x8 bfr[2];
#pragma unroll
        for (int ni = 0; ni < 2; ++ni)
          bfr[ni] = *(const s16x8*)&bufB[((kc * 2 + ni) * 64 + l) * 8];
        if (!LAST) {
#pragma unroll
          for (int mi = 0; mi < 3; ++mi)
#pragma unroll
            for (int ni = 0; ni < 2; ++ni)
              acc[mi][ni] = __builtin_amdgcn_mfma_f32_16x16x32_bf16(
                  af[kc][mi], bfr[ni], acc[mi][ni], 0, 0, 0);
        }
#pragma unroll
        for (int ni = 0; ni < 2; ++ni)
          acc[3][ni] = __builtin_amdgcn_mfma_f32_16x16x32_bf16(
              af[kc][3], bfr[ni], acc[3][ni], 0, 0, 0);
      }
      svA[f] = (f32x2){acc[3][0][0], acc[3][1][0]};  // sv (rows all equal)
      if (!LAST) {
#pragma unroll
        for (int mi = 0; mi < 3; ++mi)
#pragma unroll
          for (int j = 0; j < 4; ++j) {
            u16x2 o = {f2bf(fmaxf(acc[mi][0][j], 0.f)),
                       f2bf(fmaxf(acc[mi][1][j], 0.f))};
            *(u16x2*)(Xn + (size_t)(b * 48 + mi * 16 + lk * 4 + j) * 256 +
                      f * 32 + 2 * lr) = o;
          }
      }
    } else {
      // ---- Wg head h=f-8: msg via alpha table, g0 = relu(msg+sv), 1 u16x2 store ----
      const int h = f - 8;
      f32x4 acc[3][2];
#pragma unroll
      for (int mi = 0; mi < 3; ++mi)
#pragma unroll
        for (int ni = 0; ni < 2; ++ni) acc[mi][ni] = (f32x4){0.f, 0.f, 0.f, 0.f};
#pragma unroll
      for (int kc = 0; kc < 8; ++kc) {
        s16x8 bfr[2];
#pragma unroll
        for (int ni = 0; ni < 2; ++ni)
          bfr[ni] = *(const s16x8*)&bufB[((kc * 2 + ni) * 64 + l) * 8];
#pragma unroll
        for (int mi = 0; mi < 3; ++mi)
#pragma unroll
          for (int ni = 0; ni < 2; ++ni)
            acc[mi][ni] = __builtin_amdgcn_mfma_f32_16x16x32_bf16(
                af[kc][mi], bfr[ni], acc[mi][ni], 0, 0, 0);
      }
      float mmE = 0.f, mmO = 0.f;
#pragma unroll
      for (int mi = 0; mi < 3; ++mi)
#pragma unroll
        for (int j = 0; j < 4; ++j) {
          const float a = alphaL[w][h][mi * 16 + lk * 4 + j];
          mmE += a * acc[mi][0][j];
          mmO += a * acc[mi][1][j];
        }
      mmE = redsum_lk(mmE);
      mmO = redsum_lk(mmO);
      if (lk == 0) {
        u16x2 o = {f2bf(fmaxf(mmE + svA[h][0], 0.f)),
                   f2bf(fmaxf(mmO + svA[h][1], 0.f))};
        *(u16x2*)(GS + (size_t)b * 512 + h * 32 + 2 * lr) = o;
      }
    }
  }
#undef STAGE
}

// ---------------------------------------------------------------------------
// Generic bf16 GEMM: C[M,N] = A[M,K=256] * Bt[N,K=256]^T, 128x128, pipelined.
// EPI 2 = f32 + bias (projection).
// ---------------------------------------------------------------------------
template<int EPI>
__global__ __launch_bounds__(256)
void gemm_bt(const u16* __restrict__ A, int lda,
             const u16* __restrict__ Bt,
             float* __restrict__ Cf, int ldc, const float* __restrict__ bias) {
  __shared__ u16 ldsA[2][2 * 128 * 32];
  __shared__ u16 ldsB[2][2 * 128 * 32];
  const int tid = threadIdx.x;
  const int w = tid >> 6, l = tid & 63;
  const int wr = w >> 1, wc = w & 1;
  const int lr = l & 15, lk = l >> 4;
  const int sxor = (lr >> 1) & 3;
  const int m0 = blockIdx.x * 128, n0 = blockIdx.y * 128;

#define STAGE_AB(KT, BUF)                                                      \
  {                                                                            \
    const u16* Ag = A + (size_t)m0 * lda + (KT)*64;                            \
    const u16* Bg = Bt + (size_t)n0 * 256 + (KT)*64;                           \
    _Pragma("unroll") for (int i = 0; i < 4; ++i) {                            \
      int q = i * 256 + tid;                                                   \
      int h2 = q >> 9, r = (q >> 2) & 127, c4 = q & 3;                         \
      int c4s = c4 ^ ((r >> 1) & 3);                                           \
      gload_lds16(Ag + (size_t)r * lda + h2 * 32 + c4s * 8,                    \
                  &ldsA[BUF][(i * 256 + w * 64) * 8]);                         \
      gload_lds16(Bg + (size_t)r * 256 + h2 * 32 + c4s * 8,                    \
                  &ldsB[BUF][(i * 256 + w * 64) * 8]);                         \
    }                                                                          \
  }

  f32x4 acc[4][4];
#pragma unroll
  for (int i = 0; i < 4; ++i)
#pragma unroll
    for (int j = 0; j < 4; ++j) acc[i][j] = (f32x4){0.f, 0.f, 0.f, 0.f};

  STAGE_AB(0, 0)
#pragma unroll
  for (int kt = 0; kt < 4; ++kt) {
    __syncthreads();
    if (kt < 3) STAGE_AB(kt + 1, (kt + 1) & 1)
    const u16* bA = ldsA[kt & 1];
    const u16* bB = ldsB[kt & 1];
#pragma unroll
    for (int hh = 0; hh < 2; ++hh) {
      s16x8 af[4], bfr[4];
#pragma unroll
      for (int mi = 0; mi < 4; ++mi)
        af[mi] = *(const s16x8*)&bA[(hh * 128 + wr * 64 + mi * 16 + lr) * 32 +
                                    (lk ^ sxor) * 8];
#pragma unroll
      for (int ni = 0; ni < 4; ++ni)
        bfr[ni] = *(const s16x8*)&bB[(hh * 128 + wc * 64 + ni * 16 + lr) * 32 +
                                     (lk ^ sxor) * 8];
#pragma unroll
      for (int mi = 0; mi < 4; ++mi)
#pragma unroll
        for (int ni = 0; ni < 4; ++ni)
          acc[mi][ni] = __builtin_amdgcn_mfma_f32_16x16x32_bf16(af[mi], bfr[ni],
                                                                acc[mi][ni], 0, 0, 0);
    }
  }
#undef STAGE_AB

#pragma unroll
  for (int mi = 0; mi < 4; ++mi) {
#pragma unroll
    for (int ni = 0; ni < 4; ++ni) {
      f32x4 v = acc[mi][ni];
      int r = m0 + wr * 64 + mi * 16 + lk * 4;
      int c = n0 + wc * 64 + ni * 16 + lr;
#pragma unroll
      for (int j = 0; j < 4; ++j) {
        float fv = v[j];
        if (EPI == 0) Cf[(size_t)(r + j) * ldc + c] = fv;
        else          Cf[(size_t)(r + j) * ldc + c] = fv + bias[c];
      }
    }
  }
}

// Merged GRU-gate GEMM: blockIdx.y<6 -> G1 = g0@wx ; else G2 = state@wh. Pipelined.
__global__ __launch_bounds__(256)
void gemm_gates(const u16* __restrict__ GS, const u16* __restrict__ WXT,
                const u16* __restrict__ WHT, float* __restrict__ G1,
                float* __restrict__ G2) {
  __shared__ u16 ldsA[2][2 * 128 * 32];
  __shared__ u16 ldsB[2][2 * 128 * 32];
  const bool second = blockIdx.y >= 6;
  const u16* A = GS + (second ? 256 : 0);
  const u16* Bt = second ? WHT : WXT;
  float* Cf = second ? G2 : G1;
  const int n0 = (second ? blockIdx.y - 6 : blockIdx.y) * 128;
  const int m0 = blockIdx.x * 128;
  const int tid = threadIdx.x;
  const int w = tid >> 6, l = tid & 63;
  const int wr = w >> 1, wc = w & 1;
  const int lr = l & 15, lk = l >> 4;
  const int sxor = (lr >> 1) & 3;

#define STAGE_AB(KT, BUF)                                                      \
  {                                                                            \
    const u16* Ag = A + (size_t)m0 * 512 + (KT)*64;                            \
    const u16* Bg = Bt + (size_t)n0 * 256 + (KT)*64;                           \
    _Pragma("unroll") for (int i = 0; i < 4; ++i) {                            \
      int q = i * 256 + tid;                                                   \
      int h2 = q >> 9, r = (q >> 2) & 127, c4 = q & 3;                         \
      int c4s = c4 ^ ((r >> 1) & 3);                                           \
      gload_lds16(Ag + (size_t)r * 512 + h2 * 32 + c4s * 8,                    \
                  &ldsA[BUF][(i * 256 + w * 64) * 8]);                         \
      gload_lds16(Bg + (size_t)r * 256 + h2 * 32 + c4s * 8,                    \
                  &ldsB[BUF][(i * 256 + w * 64) * 8]);                         \
    }                                                                          \
  }

  f32x4 acc[4][4];
#pragma unroll
  for (int i = 0; i < 4; ++i)
#pragma unroll
    for (int j = 0; j < 4; ++j) acc[i][j] = (f32x4){0.f, 0.f, 0.f, 0.f};

  STAGE_AB(0, 0)
#pragma unroll
  for (int kt = 0; kt < 4; ++kt) {
    __syncthreads();
    if (kt < 3) STAGE_AB(kt + 1, (kt + 1) & 1)
    const u16* bA = ldsA[kt & 1];
    const u16* bB = ldsB[kt & 1];
#pragma unroll
    for (int hh = 0; hh < 2; ++hh) {
      s16x8 af[4], bfr[4];
#pragma unroll
      for (int mi = 0; mi < 4; ++mi)
        af[mi] = *(const s16x8*)&bA[(hh * 128 + wr * 64 + mi * 16 + lr) * 32 +
                                    (lk ^ sxor) * 8];
#pragma unroll
      for (int ni = 0; ni < 4; ++ni)
        bfr[ni] = *(const s16x8*)&bB[(hh * 128 + wc * 64 + ni * 16 + lr) * 32 +
                                     (lk ^ sxor) * 8];
#pragma unroll
      for (int mi = 0; mi < 4; ++mi)
#pragma unroll
        for (int ni = 0; ni < 4; ++ni)
          acc[mi][ni] = __builtin_amdgcn_mfma_f32_16x16x32_bf16(af[mi], bfr[ni],
                                                                acc[mi][ni], 0, 0, 0);
    }
  }
#undef STAGE_AB

#pragma unroll
  for (int mi = 0; mi < 4; ++mi) {
#pragma unroll
    for (int ni = 0; ni < 4; ++ni) {
      f32x4 v = acc[mi][ni];
      int r = m0 + wr * 64 + mi * 16 + lk * 4;
      int c = n0 + wc * 64 + ni * 16 + lr;
#pragma unroll
      for (int j = 0; j < 4; ++j)
        Cf[(size_t)(r + j) * 768 + c] = v[j];
    }
  }
}

// One-shot transpose-convert: WXT, WHT, PRJ  (out[N][K] bf16 from in[K][N] f32)
__global__ void pack_all(const float* __restrict__ wx, const float* __restrict__ wh,
                         const float* __restrict__ pw,
                         u16* __restrict__ WXT, u16* __restrict__ WHT,
                         u16* __restrict__ PRJ) {
  int idx = blockIdx.x * 256 + threadIdx.x;
  const float* src; u16* dst; int N; int li;
  if (idx < 196608)       { src = wx; dst = WXT; N = 768; li = idx; }
  else if (idx < 393216)  { src = wh; dst = WHT; N = 768; li = idx - 196608; }
  else                    { src = pw; dst = PRJ; N = 256; li = idx - 393216; }
  int n = li >> 8, k = li & 255;
  dst[li] = f2bf(src[(size_t)k * N + n]);
}

// Fragment-major packing of [Wg | Ws] in 32-col strips, even/odd within strip:
// chunk c: l=c&63, ni=(c>>6)&1, kc=(c>>7)&7, s=c>>10; col n = s*32 + 2*(l&15) + ni.
__global__ void pack_bp(const float* __restrict__ Wg, const float* __restrict__ Ws,
                        u16* __restrict__ BP) {
  int c = blockIdx.x * 256 + threadIdx.x;  // 16384 chunks
  int l = c & 63, ni = (c >> 6) & 1, kc = (c >> 7) & 7, s = c >> 10;
  int n = s * 32 + ((l & 15) << 1) + ni;
  int k0 = kc * 32 + (l >> 4) * 8;
  const float* W = (n < 256) ? Wg : Ws;
  int nn = n & 255;
  u16x8 o;
#pragma unroll
  for (int e = 0; e < 8; ++e) o[e] = f2bf(W[(size_t)(k0 + e) * 256 + nn]);
  *(u16x8*)(BP + (size_t)c * 8) = o;
}

// WGAD[d][h] = sum_j Wg[d][h*32+j]*adst[h*32+j];  WGAS likewise with asrc.
__global__ void wgad_kernel(const float* __restrict__ Wg, const float* __restrict__ adst,
                            const float* __restrict__ asrc,
                            float* __restrict__ WGAD, float* __restrict__ WGAS) {
  const int h = blockIdx.x, d = threadIdx.x;
  float sd = 0.f, ss = 0.f;
#pragma unroll
  for (int j = 0; j < 32; ++j) {
    float wv = Wg[(size_t)d * 256 + h * 32 + j];
    sd += wv * adst[h * 32 + j];
    ss += wv * asrc[h * 32 + j];
  }
  WGAD[(size_t)d * 8 + h] = sd;
  WGAS[(size_t)d * 8 + h] = ss;
}

// B-fragment pack for E-phase MFMA: cols 0-7 = WGAS heads, cols 8-15 = WGAD heads.
__global__ void pack_ep(const float* __restrict__ WGAS, const float* __restrict__ WGAD,
                        u16* __restrict__ EP) {
  int c = blockIdx.x * 256 + threadIdx.x;  // 512 chunks
  if (c >= 512) return;
  int l = c & 63, kc = c >> 6;
  int hh = l & 15, k0 = kc * 32 + (l >> 4) * 8;
  u16x8 o;
#pragma unroll
  for (int e = 0; e < 8; ++e)
    o[e] = (hh < 8) ? f2bf(WGAS[(size_t)(k0 + e) * 8 + hh])
                    : f2bf(WGAD[(size_t)(k0 + e) * 8 + (hh - 8)]);
  *(u16x8*)(EP + (size_t)c * 8) = o;
}

// x0 bf16 + virtual sum -> state f32/bf16
__global__ __launch_bounds__(256)
void prep_x_kernel(const float* __restrict__ nf, u16* __restrict__ X0,
                   float* __restrict__ state, u16* __restrict__ GS) {
  __shared__ f32x4 part[4][64];
  const int b = blockIdx.x, t = threadIdx.x;
  const int c4 = t & 63, sg = t >> 6;
  const f32x4* src = (const f32x4*)(nf + (size_t)b * 48 * 256);
  f32x4 acc = (f32x4){0.f, 0.f, 0.f, 0.f};
  for (int s = sg * 12; s < sg * 12 + 12; ++s) {
    f32x4 v = src[(size_t)s * 64 + c4];
    acc += v;
    u16x4 o = {f2bf(v[0]), f2bf(v[1]), f2bf(v[2]), f2bf(v[3])};
    *(u16x4*)(X0 + ((size_t)b * 48 + s) * 256 + c4 * 4) = o;
  }
  part[sg][c4] = acc;
  __syncthreads();
  if (t < 64) {
    f32x4 r = part[0][t] + part[1][t] + part[2][t] + part[3][t];
#pragma unroll
    for (int j = 0; j < 4; ++j) {
      int d = t * 4 + j;
      state[(size_t)b * 256 + d] = r[j];
      GS[(size_t)b * 512 + 256 + d] = f2bf(r[j]);
    }
  }
}

// GRU elementwise (pure)
__global__ void gru_kernel(const float* __restrict__ G1, const float* __restrict__ G2,
                           const float* __restrict__ bx, const float* __restrict__ bh,
                           float* __restrict__ state, u16* __restrict__ GS) {
  const int b = blockIdx.x, d = threadIdx.x;
  const float* g1 = G1 + (size_t)b * 768;
  const float* g2 = G2 + (size_t)b * 768;
  float xz = g1[d] + bx[d], xr = g1[256 + d] + bx[256 + d], xh = g1[512 + d] + bx[512 + d];
  float hz = g2[d] + bh[d], hr = g2[256 + d] + bh[256 + d], hh2 = g2[512 + d] + bh[512 + d];
  float z = 1.f / (1.f + expf(-(xz + hz)));
  float r = 1.f / (1.f + expf(-(xr + hr)));
  float n = tanhf(xh + r * hh2);
  float h0 = state[b * 256 + d];
  float sn = z * h0 + (1.f - z) * n;
  state[b * 256 + d] = sn;
  GS[(size_t)b * 512 + 256 + d] = f2bf(sn);
}

extern "C" void kernel_launch(void* const* d_in, const int* in_sizes, int n_in,
                              void* d_out, int out_size, void* d_ws, size_t ws_size,
                              hipStream_t stream) {
  const float* nf  = (const float*)d_in[0];
  const float* Wg  = (const float*)d_in[2];
  const float* Ws  = (const float*)d_in[3];
  const float* asr = (const float*)d_in[4];
  const float* ads = (const float*)d_in[5];
  const float* wx  = (const float*)d_in[6];
  const float* wh  = (const float*)d_in[7];
  const float* bx  = (const float*)d_in[8];
  const float* bh  = (const float*)d_in[9];
  const float* pw  = (const float*)d_in[10];
  const float* pb  = (const float*)d_in[11];
  float* out = (float*)d_out;

  char* p = (char*)d_ws;
  size_t off = 0;
  auto alloc = [&](size_t bytes) { char* r = p + off; off += (bytes + 255) & ~255ULL; return r; };
  u16* WXT   = (u16*)alloc(768 * 256 * 2);
  u16* WHT   = (u16*)alloc(768 * 256 * 2);
  u16* PRJ   = (u16*)alloc(256 * 256 * 2);
  u16* BP    = (u16*)alloc(512 * 256 * 2);            // [Wg|Ws] 32-col strip pack
  u16* EP    = (u16*)alloc(512 * 8 * 2);              // [WGAS|WGAD] fragment pack
  float* WGAD = (float*)alloc(256 * 8 * 4);
  float* WGAS = (float*)alloc(256 * 8 * 4);
  u16* X0    = (u16*)alloc((size_t)98304 * 256 * 2);
  u16* X1    = (u16*)alloc((size_t)98304 * 256 * 2);
  float* G1   = (float*)alloc((size_t)2048 * 768 * 4);
  float* G2   = (float*)alloc((size_t)2048 * 768 * 4);
  u16* GS     = (u16*)alloc((size_t)2048 * 512 * 2);  // [g0 | state] bf16
  float* ST   = (float*)alloc((size_t)2048 * 256 * 4);

  pack_all<<<1792, 256, 0, stream>>>(wx, wh, pw, WXT, WHT, PRJ);
  pack_bp<<<64, 256, 0, stream>>>(Wg, Ws, BP);
  wgad_kernel<<<8, 256, 0, stream>>>(Wg, ads, asr, WGAD, WGAS);
  pack_ep<<<2, 256, 0, stream>>>(WGAS, WGAD, EP);
  prep_x_kernel<<<2048, 256, 0, stream>>>(nf, X0, ST, GS);

  u16* xc = X0; u16* xn = X1;
  for (int t = 0; t < 4; ++t) {
    // fused: sv (mi=3, Ws-first) + E-phase attention (e_src + e_dst) + g0 (+ xnext)
    if (t < 3) fused_step<false><<<1024, 128, 0, stream>>>(xc, BP, EP, GS, xn);
    else       fused_step<true ><<<1024, 128, 0, stream>>>(xc, BP, EP, GS, nullptr);
    // GRU gates (both in one launch)
    gemm_gates<<<dim3(16, 12), 256, 0, stream>>>(GS, WXT, WHT, G1, G2);
    // GRU elementwise
    gru_kernel<<<2048, 256, 0, stream>>>(G1, G2, bx, bh, ST, GS);
    u16* tmp = xc; xc = xn; xn = tmp;
  }
  // out = state @ proj_w + proj_b
  gemm_bt<2><<<dim3(16, 2), 256, 0, stream>>>(GS + 256, 512, PRJ, out, 256, pb);
}